// Round 6
// baseline (404.189 us; speedup 1.0000x reference)
//
#include <hip/hip_runtime.h>
#include <hip/hip_bf16.h>

#define N_NODES 50000
#define IN_CH 128
#define HID 128
#define OUT_CH 64
#define N_EDGES 800000
#define N_TOT_EDGES (N_EDGES + N_NODES)   // + self loops

// ---------------- CSR build ----------------

__global__ void k_init(int* cnt, int* cur, float* als1, float* ald1,
                       float* als2, float* ald2, int n) {
    int i = blockIdx.x * 256 + threadIdx.x;
    if (i < n) {
        cnt[i] = 1; cur[i] = 0;           // self-loop contributes 1
        als1[i] = 0.f; ald1[i] = 0.f;     // atomic-dot accumulators
        als2[i] = 0.f; ald2[i] = 0.f;
    }
}

__global__ void k_count(const int* __restrict__ dst_row, int* __restrict__ cnt, int e) {
    int i = blockIdx.x * 256 + threadIdx.x;
    if (i < e) atomicAdd(&cnt[dst_row[i]], 1);
}

// inclusive scan of cnt -> off[i+1]; per-block sums to bsum
__global__ void k_scan1(const int* __restrict__ cnt, int* __restrict__ off,
                        int* __restrict__ bsum, int n) {
    __shared__ int s[256];
    int t = threadIdx.x;
    int i = blockIdx.x * 256 + t;
    int v = (i < n) ? cnt[i] : 0;
    s[t] = v;
    __syncthreads();
    for (int d = 1; d < 256; d <<= 1) {
        int x = (t >= d) ? s[t - d] : 0;
        __syncthreads();
        s[t] += x;
        __syncthreads();
    }
    if (i < n) off[i + 1] = s[t];
    if (t == 255) bsum[blockIdx.x] = s[255];
}

__global__ void k_scan2(int* __restrict__ bsum, int nb) {  // single block, nb <= 256
    __shared__ int s[256];
    int t = threadIdx.x;
    int v = (t < nb) ? bsum[t] : 0;
    s[t] = v;
    __syncthreads();
    for (int d = 1; d < 256; d <<= 1) {
        int x = (t >= d) ? s[t - d] : 0;
        __syncthreads();
        s[t] += x;
        __syncthreads();
    }
    if (t < nb) bsum[t] = s[t] - v;  // exclusive prefix
}

__global__ void k_scan3(int* __restrict__ off, const int* __restrict__ bsum, int n) {
    int i = blockIdx.x * 256 + threadIdx.x;
    if (i < n) off[i + 1] += bsum[blockIdx.x];
    if (i == 0) off[0] = 0;
}

__global__ void k_fill(const int* __restrict__ ei, const int* __restrict__ off,
                       int* __restrict__ cur, int* __restrict__ csr, int e, int n) {
    int i = blockIdx.x * 256 + threadIdx.x;
    if (i >= e + n) return;
    int src, dst;
    if (i < e) { src = ei[i]; dst = ei[e + i]; }
    else       { src = dst = i - e; }
    int pos = off[dst] + atomicAdd(&cur[dst], 1);
    csr[pos] = src;
}

// ---------------- GEMM (h = X @ W) + fused attention dots ----------------
// LDS-free: 64-row x 64-col tile per 256-thread block; thread = 4 rows x 4 cols.
// X float4 loads are 16-lane-broadcast (same addr within a col-group) -> 1 fetch;
// W loads are 256B-coalesced per k; both L1/L2-served, no barriers, high occupancy.
// H written CHUNK-MAJOR Hc[chunk][row][16] (chunk = 16 feats = 3.2MB, XCD-L2-resident
// for the SpMM). Attention dots: per-tile partials -> atomicAdd into zeroed als/ald.
template<int N>
__global__ __launch_bounds__(256) void gemm_att(
        const float* __restrict__ X, const float* __restrict__ W,
        const float* __restrict__ asrc, const float* __restrict__ adst,
        float* __restrict__ Hc, float* __restrict__ als, float* __restrict__ ald,
        int M) {
    constexpr int K = 128;
    constexpr int CT = N / 64;                 // col tiles (2 or 1)
    const int ct = blockIdx.x % CT;
    const int r0 = (blockIdx.x / CT) * 64;
    const int t  = threadIdx.x;
    const int c  = t & 15;                     // col group in tile
    const int rg = t >> 4;                     // row group 0..15
    const int col = ct * 64 + c * 4;

    // clamp OOB rows to M-1 (results discarded at write)
    const float* Xr[4];
    #pragma unroll
    for (int r = 0; r < 4; ++r) {
        int row = r0 + rg * 4 + r; if (row >= M) row = M - 1;
        Xr[r] = X + (size_t)row * K;
    }

    float acc[4][4] = {};
    for (int k0 = 0; k0 < K; k0 += 4) {
        float4 xv[4], wv[4];
        #pragma unroll
        for (int r = 0; r < 4; ++r) xv[r] = *(const float4*)&Xr[r][k0];
        #pragma unroll
        for (int u = 0; u < 4; ++u) wv[u] = *(const float4*)&W[(size_t)(k0 + u) * N + col];
        #pragma unroll
        for (int r = 0; r < 4; ++r) {
            float xa[4] = {xv[r].x, xv[r].y, xv[r].z, xv[r].w};
            #pragma unroll
            for (int u = 0; u < 4; ++u) {
                acc[r][0] += xa[u] * wv[u].x;
                acc[r][1] += xa[u] * wv[u].y;
                acc[r][2] += xa[u] * wv[u].z;
                acc[r][3] += xa[u] * wv[u].w;
            }
        }
    }

    const float as0 = asrc[col], as1 = asrc[col+1], as2 = asrc[col+2], as3 = asrc[col+3];
    const float ad0 = adst[col], ad1 = adst[col+1], ad2 = adst[col+2], ad3 = adst[col+3];
    const size_t cstride = (size_t)M * 16;
    float* __restrict__ Hq = Hc + (size_t)(col >> 4) * cstride + (col & 15);
    #pragma unroll
    for (int r = 0; r < 4; ++r) {
        int row = r0 + rg * 4 + r;
        float ps = acc[r][0]*as0 + acc[r][1]*as1 + acc[r][2]*as2 + acc[r][3]*as3;
        float pd = acc[r][0]*ad0 + acc[r][1]*ad1 + acc[r][2]*ad2 + acc[r][3]*ad3;
        #pragma unroll
        for (int mask = 1; mask < 16; mask <<= 1) {   // reduce over the 16 col-groups
            ps += __shfl_xor(ps, mask);
            pd += __shfl_xor(pd, mask);
        }
        if (row < M) {
            *(float4*)&Hq[(size_t)row * 16] =
                make_float4(acc[r][0], acc[r][1], acc[r][2], acc[r][3]);
            if (c == 0) {
                atomicAdd(&als[row], ps);   // partial over this 64-col tile
                atomicAdd(&ald[row], pd);
            }
        }
    }
}

// ---------------- edge weights: packed u32 = (src<<16) | bf16(exp(leaky(e))) ----
// src < 65536 (N_NODES=50000) so 16 bits suffice. Denominator sums the ROUNDED
// bf16 weights so numerator/denominator are exactly consistent.
// No segment-max: scores are glorot-scale dot products (|e| < ~10), exp() is
// f32-safe and softmax ratios identical to the max-subtracted reference.
__global__ __launch_bounds__(256) void k_edgew(
        const float* __restrict__ als, const float* __restrict__ ald,
        const int* __restrict__ off, const int* __restrict__ csr,
        unsigned* __restrict__ ew, float* __restrict__ invden, int n) {
    const int fl = threadIdx.x & 15;
    const int v = blockIdx.x * 16 + (threadIdx.x >> 4);
    if (v >= n) return;
    const int start = off[v], end = off[v + 1];
    const float aldv = ald[v];
    float s = 0.f;
    for (int j = start + fl; j < end; j += 16) {
        int src = csr[j];
        float e = als[src] + aldv;
        e = e > 0.f ? e : 0.2f * e;
        float w = __expf(e);
        unsigned u = __float_as_uint(w);
        unsigned r = (u + 0x7fffu + ((u >> 16) & 1u)) >> 16;   // RNE to bf16
        ew[j] = ((unsigned)src << 16) | r;
        s += __uint_as_float(r << 16);
    }
    #pragma unroll
    for (int d = 1; d < 16; d <<= 1) s += __shfl_xor(s, d);
    if (fl == 0) invden[v] = 1.f / (s + 1e-16f);
}

// ---------------- chunked SpMM: out[v] = invden * sum_e w_e * Hc[src_e] ------------
// One wave per (node, chunk); lanes = 4 edge-subs x 16 features.
// chunk = blockIdx.x % NCH -> round-robin block->XCD dispatch pins each chunk's
// 3.2MB Hc slice to one XCD's L2.
// Each sub's 16 lanes load ew[j] at the SAME address (broadcast fetch, no shfl,
// no cross-lane ops inside the loop -> per-sub trip counts may diverge safely).
// 2-way unrolled: 8 independent H-gathers in flight per wave.
template<int F, bool RELU>
__global__ __launch_bounds__(256) void k_spmm(
        const float* __restrict__ Hc, const unsigned* __restrict__ ew,
        const float* __restrict__ invden, const float* __restrict__ bias,
        const int* __restrict__ off, float* __restrict__ out, int n) {
    constexpr int NCH = F / 16;
    const int chunk = blockIdx.x % NCH;
    const int v = (blockIdx.x / NCH) * 4 + (threadIdx.x >> 6);
    if (v >= n) return;
    const int lane = threadIdx.x & 63;
    const int sub = lane >> 4, fl = lane & 15;
    const int start = off[v], end = off[v + 1];
    const float* __restrict__ Hch = Hc + (size_t)chunk * (size_t)n * 16 + fl;

    float a0 = 0.f, a1 = 0.f;
    int j = start + sub;
    for (; j + 4 < end; j += 8) {
        unsigned e0 = ew[j];
        unsigned e1 = ew[j + 4];
        float h0 = Hch[(size_t)(e0 >> 16) * 16];
        float h1 = Hch[(size_t)(e1 >> 16) * 16];
        a0 += __uint_as_float(e0 << 16) * h0;
        a1 += __uint_as_float(e1 << 16) * h1;
    }
    if (j < end) {
        unsigned e0 = ew[j];
        a0 += __uint_as_float(e0 << 16) * Hch[(size_t)(e0 >> 16) * 16];
    }
    float acc = a0 + a1;                       // all 64 lanes reconverged here
    acc += __shfl_xor(acc, 16);
    acc += __shfl_xor(acc, 32);
    if (sub == 0) {
        float o = acc * invden[v] + bias[chunk * 16 + fl];
        if (RELU) o = fmaxf(o, 0.f);
        out[(size_t)v * F + chunk * 16 + fl] = o;
    }
}

// ---------------- launch ----------------

extern "C" void kernel_launch(void* const* d_in, const int* in_sizes, int n_in,
                              void* d_out, int out_size, void* d_ws, size_t ws_size,
                              hipStream_t stream) {
    const float* x     = (const float*)d_in[0];
    const int*   ei    = (const int*)d_in[1];
    const float* W1    = (const float*)d_in[2];
    const float* as1   = (const float*)d_in[3];
    const float* ad1   = (const float*)d_in[4];
    const float* b1    = (const float*)d_in[5];
    const float* W2    = (const float*)d_in[6];
    const float* as2   = (const float*)d_in[7];
    const float* ad2   = (const float*)d_in[8];
    const float* b2    = (const float*)d_in[9];
    float* out = (float*)d_out;

    const int Nn = N_NODES, E = N_EDGES, ET = N_TOT_EDGES;

    // workspace carve-up (256B aligned)
    char* ws = (char*)d_ws;
    size_t o = 0;
    auto carve = [&](size_t bytes) { char* p = ws + o; o = (o + bytes + 255) & ~(size_t)255; return p; };
    int*      off  = (int*)carve((Nn + 1) * sizeof(int));
    int*      cnt  = (int*)carve(Nn * sizeof(int));
    int*      cur  = (int*)carve(Nn * sizeof(int));
    int*      bsum = (int*)carve(256 * sizeof(int));
    int*      csr  = (int*)carve((size_t)ET * sizeof(int));
    unsigned* ew   = (unsigned*)carve((size_t)ET * sizeof(unsigned));
    float*    h1   = (float*)carve((size_t)Nn * HID * sizeof(float));  // chunk-major; reused as h2
    float*    alsA = (float*)carve(Nn * sizeof(float));
    float*    aldA = (float*)carve(Nn * sizeof(float));
    float*    alsB = (float*)carve(Nn * sizeof(float));
    float*    aldB = (float*)carve(Nn * sizeof(float));
    float*    invd = (float*)carve(Nn * sizeof(float));
    float*    y1   = (float*)carve((size_t)Nn * HID * sizeof(float));
    float*    h2   = h1;

    const int nbN  = (Nn + 255) / 256;
    const int nbE  = (E + 255) / 256;
    const int nbET = (ET + 255) / 256;

    // CSR build
    k_init<<<nbN, 256, 0, stream>>>(cnt, cur, alsA, aldA, alsB, aldB, Nn);
    k_count<<<nbE, 256, 0, stream>>>(ei + E, cnt, E);
    k_scan1<<<nbN, 256, 0, stream>>>(cnt, off, bsum, Nn);
    k_scan2<<<1, 256, 0, stream>>>(bsum, nbN);
    k_scan3<<<nbN, 256, 0, stream>>>(off, bsum, Nn);
    k_fill<<<nbET, 256, 0, stream>>>(ei, off, cur, csr, E, Nn);

    const int nbEW = (Nn + 15) / 16;
    const int nbNode4 = (Nn + 3) / 4;
    const int nbRT = (Nn + 63) / 64;          // 64-row tiles

    // layer 1
    gemm_att<HID><<<nbRT * (HID / 64), 256, 0, stream>>>(x, W1, as1, ad1, h1, alsA, aldA, Nn);
    k_edgew<<<nbEW, 256, 0, stream>>>(alsA, aldA, off, csr, ew, invd, Nn);
    k_spmm<HID, true><<<nbNode4 * (HID / 16), 256, 0, stream>>>(
        h1, ew, invd, b1, off, y1, Nn);

    // layer 2
    gemm_att<OUT_CH><<<nbRT * (OUT_CH / 64), 256, 0, stream>>>(y1, W2, as2, ad2, h2, alsB, aldB, Nn);
    k_edgew<<<nbEW, 256, 0, stream>>>(alsB, aldB, off, csr, ew, invd, Nn);
    k_spmm<OUT_CH, false><<<nbNode4 * (OUT_CH / 16), 256, 0, stream>>>(
        h2, ew, invd, b2, off, out, Nn);
}

// Round 7
// 353.058 us; speedup vs baseline: 1.1448x; 1.1448x over previous
//
#include <hip/hip_runtime.h>
#include <hip/hip_bf16.h>

#define N_NODES 50000
#define IN_CH 128
#define HID 128
#define OUT_CH 64
#define N_EDGES 800000
#define N_TOT_EDGES (N_EDGES + N_NODES)   // + self loops

// ---------------- CSR build ----------------

__global__ void k_init_cnt(int* cnt, int* cur, int n) {
    int i = blockIdx.x * 256 + threadIdx.x;
    if (i < n) { cnt[i] = 1; cur[i] = 0; }   // self-loop contributes 1
}

__global__ void k_count(const int* __restrict__ dst_row, int* __restrict__ cnt, int e) {
    int i = blockIdx.x * 256 + threadIdx.x;
    if (i < e) atomicAdd(&cnt[dst_row[i]], 1);
}

// inclusive scan of cnt -> off[i+1]; per-block sums to bsum
__global__ void k_scan1(const int* __restrict__ cnt, int* __restrict__ off,
                        int* __restrict__ bsum, int n) {
    __shared__ int s[256];
    int t = threadIdx.x;
    int i = blockIdx.x * 256 + t;
    int v = (i < n) ? cnt[i] : 0;
    s[t] = v;
    __syncthreads();
    for (int d = 1; d < 256; d <<= 1) {
        int x = (t >= d) ? s[t - d] : 0;
        __syncthreads();
        s[t] += x;
        __syncthreads();
    }
    if (i < n) off[i + 1] = s[t];
    if (t == 255) bsum[blockIdx.x] = s[255];
}

__global__ void k_scan2(int* __restrict__ bsum, int nb) {  // single block, nb <= 256
    __shared__ int s[256];
    int t = threadIdx.x;
    int v = (t < nb) ? bsum[t] : 0;
    s[t] = v;
    __syncthreads();
    for (int d = 1; d < 256; d <<= 1) {
        int x = (t >= d) ? s[t - d] : 0;
        __syncthreads();
        s[t] += x;
        __syncthreads();
    }
    if (t < nb) bsum[t] = s[t] - v;  // exclusive prefix
}

__global__ void k_scan3(int* __restrict__ off, const int* __restrict__ bsum, int n) {
    int i = blockIdx.x * 256 + threadIdx.x;
    if (i < n) off[i + 1] += bsum[blockIdx.x];
    if (i == 0) off[0] = 0;
}

__global__ void k_fill(const int* __restrict__ ei, const int* __restrict__ off,
                       int* __restrict__ cur, int* __restrict__ csr, int e, int n) {
    int i = blockIdx.x * 256 + threadIdx.x;
    if (i >= e + n) return;
    int src, dst;
    if (i < e) { src = ei[i]; dst = ei[e + i]; }
    else       { src = dst = i - e; }
    int pos = off[dst] + atomicAdd(&cur[dst], 1);
    csr[pos] = src;
}

// ---------------- GEMM (h = X @ W) + fused attention dots ----------------
// (round-5 structure: W + X^T staged in LDS; best measured so far.)
// H is written CHUNK-MAJOR: Hc[chunk][row][16] so the SpMM can keep one
// 3.2MB chunk resident in a single XCD's 4MB L2.
template<int N>
__global__ __launch_bounds__(256) void gemm_att(
        const float* __restrict__ X, const float* __restrict__ W,
        const float* __restrict__ asrc, const float* __restrict__ adst,
        float* __restrict__ Hc, float* __restrict__ als, float* __restrict__ ald,
        int M) {
    constexpr int K = 128;
    constexpr int TPR = N / 4;             // threads per row (32 or 16)
    constexpr int RPB = (256 / TPR) * 4;   // rows per block (32 or 64)
    __shared__ float Ws[K * N];
    __shared__ float Xt[K * RPB];          // transposed: Xt[k][row_local]
    const int t = threadIdx.x;
    const int r0 = blockIdx.x * RPB;

    for (int i = t * 4; i < K * N; i += 1024)
        *(float4*)&Ws[i] = *(const float4*)&W[i];
    for (int i = t * 4; i < RPB * K; i += 1024) {
        int rl = i / K, k0 = i % K;
        int row = r0 + rl;
        float4 v = make_float4(0.f, 0.f, 0.f, 0.f);
        if (row < M) v = *(const float4*)&X[(size_t)row * K + k0];
        Xt[(k0 + 0) * RPB + rl] = v.x;
        Xt[(k0 + 1) * RPB + rl] = v.y;
        Xt[(k0 + 2) * RPB + rl] = v.z;
        Xt[(k0 + 3) * RPB + rl] = v.w;
    }
    __syncthreads();

    const int col = (t % TPR) * 4;
    const int rg  = (t / TPR) * 4;
    float acc[4][4] = {};
    for (int k = 0; k < K; ++k) {
        float4 xv = *(const float4*)&Xt[k * RPB + rg];
        float4 wv = *(const float4*)&Ws[k * N + col];
        float xa[4] = {xv.x, xv.y, xv.z, xv.w};
        #pragma unroll
        for (int r = 0; r < 4; ++r) {
            acc[r][0] += xa[r] * wv.x;
            acc[r][1] += xa[r] * wv.y;
            acc[r][2] += xa[r] * wv.z;
            acc[r][3] += xa[r] * wv.w;
        }
    }

    float as0 = asrc[col], as1 = asrc[col+1], as2 = asrc[col+2], as3 = asrc[col+3];
    float ad0 = adst[col], ad1 = adst[col+1], ad2 = adst[col+2], ad3 = adst[col+3];
    const size_t cstride = (size_t)M * 16;
    #pragma unroll
    for (int r = 0; r < 4; ++r) {
        int row = r0 + rg + r;
        float ps = acc[r][0]*as0 + acc[r][1]*as1 + acc[r][2]*as2 + acc[r][3]*as3;
        float pd = acc[r][0]*ad0 + acc[r][1]*ad1 + acc[r][2]*ad2 + acc[r][3]*ad3;
        #pragma unroll
        for (int mask = 1; mask < TPR; mask <<= 1) {
            ps += __shfl_xor(ps, mask);
            pd += __shfl_xor(pd, mask);
        }
        if (row < M) {
            *(float4*)&Hc[(size_t)(col >> 4) * cstride + (size_t)row * 16 + (col & 15)] =
                make_float4(acc[r][0], acc[r][1], acc[r][2], acc[r][3]);
            if ((t % TPR) == 0) { als[row] = ps; ald[row] = pd; }
        }
    }
}

// ---------------- edge weights: packed u32 = (src<<16) | bf16(exp(leaky(e))) ----
// src < 65536 (N_NODES=50000) so 16 bits suffice. Denominator sums the ROUNDED
// bf16 weights so numerator/denominator are exactly consistent.
// No segment-max: scores are glorot-scale dot products (|e| < ~10), exp() is
// f32-safe and softmax ratios identical to the max-subtracted reference.
__global__ __launch_bounds__(256) void k_edgew(
        const float* __restrict__ als, const float* __restrict__ ald,
        const int* __restrict__ off, const int* __restrict__ csr,
        unsigned* __restrict__ ew, float* __restrict__ invden, int n) {
    const int fl = threadIdx.x & 15;
    const int v = blockIdx.x * 16 + (threadIdx.x >> 4);
    if (v >= n) return;
    const int start = off[v], end = off[v + 1];
    const float aldv = ald[v];
    float s = 0.f;
    for (int j = start + fl; j < end; j += 16) {
        int src = csr[j];
        float e = als[src] + aldv;
        e = e > 0.f ? e : 0.2f * e;
        float w = __expf(e);
        unsigned u = __float_as_uint(w);
        unsigned r = (u + 0x7fffu + ((u >> 16) & 1u)) >> 16;   // RNE to bf16
        ew[j] = ((unsigned)src << 16) | r;
        s += __uint_as_float(r << 16);
    }
    #pragma unroll
    for (int d = 1; d < 16; d <<= 1) s += __shfl_xor(s, d);
    if (fl == 0) invden[v] = 1.f / (s + 1e-16f);
}

// ---------------- chunked SpMM: out[v] = invden * sum_e w_e * Hc[src_e] ------------
// One wave per (node, chunk). Lane = (edge-slot eq = lane>>2) x (feat-quad q = lane&3).
// Per iteration, the wave processes 16 EDGES with exactly TWO memory instructions:
//   - ew dword load: 16 slots, quad-broadcast, 1 cache line total
//   - H float4 gather: each edge's 64B line read by its 4 quad lanes (coalesced);
//     16 independent lines in flight from ONE instruction.
// Padding slots use a clamped ew address + w=0 predication (per-lane only -> no
// exec-mask/shfl hazard; wasted FMAs multiply by 0 on an L1-hot line).
// chunk = blockIdx.x % NCH -> round-robin block->XCD dispatch pins each chunk's
// 3.2MB Hc slice to one XCD's L2 (validated: FETCH ~= compulsory in r6).
template<int F, bool RELU>
__global__ __launch_bounds__(256) void k_spmm(
        const float* __restrict__ Hc, const unsigned* __restrict__ ew,
        const float* __restrict__ invden, const float* __restrict__ bias,
        const int* __restrict__ off, float* __restrict__ out, int n) {
    constexpr int NCH = F / 16;
    const int chunk = blockIdx.x % NCH;
    const int v = (blockIdx.x / NCH) * 4 + (threadIdx.x >> 6);
    if (v >= n) return;
    const int lane = threadIdx.x & 63;
    const int eq = lane >> 2;                  // edge slot 0..15
    const int q  = lane & 3;                   // feature quad 0..3
    const int start = off[v], end = off[v + 1];
    const float* __restrict__ Hch = Hc + (size_t)chunk * (size_t)n * 16 + q * 4;

    float ax = 0.f, ay = 0.f, az = 0.f, aw = 0.f;
    for (int base = start; base < end; base += 16) {   // wave-uniform bound
        int j = base + eq;
        unsigned e = ew[j < end ? j : end - 1];        // clamped (deg >= 1 always)
        float w = (j < end) ? __uint_as_float(e << 16) : 0.f;
        float4 h = *(const float4*)&Hch[(size_t)(e >> 16) * 16];
        ax += w * h.x;
        ay += w * h.y;
        az += w * h.z;
        aw += w * h.w;
    }
    // reduce over the 16 edge slots (lane bits 2..5); all 64 lanes active
    #pragma unroll
    for (int m = 4; m <= 32; m <<= 1) {
        ax += __shfl_xor(ax, m);
        ay += __shfl_xor(ay, m);
        az += __shfl_xor(az, m);
        aw += __shfl_xor(aw, m);
    }
    if (eq == 0) {
        const float inv = invden[v];
        const float4 b = *(const float4*)&bias[chunk * 16 + q * 4];
        float4 o;
        o.x = ax * inv + b.x;
        o.y = ay * inv + b.y;
        o.z = az * inv + b.z;
        o.w = aw * inv + b.w;
        if (RELU) {
            o.x = fmaxf(o.x, 0.f); o.y = fmaxf(o.y, 0.f);
            o.z = fmaxf(o.z, 0.f); o.w = fmaxf(o.w, 0.f);
        }
        *(float4*)&out[(size_t)v * F + chunk * 16 + q * 4] = o;
    }
}

// ---------------- launch ----------------

extern "C" void kernel_launch(void* const* d_in, const int* in_sizes, int n_in,
                              void* d_out, int out_size, void* d_ws, size_t ws_size,
                              hipStream_t stream) {
    const float* x     = (const float*)d_in[0];
    const int*   ei    = (const int*)d_in[1];
    const float* W1    = (const float*)d_in[2];
    const float* as1   = (const float*)d_in[3];
    const float* ad1   = (const float*)d_in[4];
    const float* b1    = (const float*)d_in[5];
    const float* W2    = (const float*)d_in[6];
    const float* as2   = (const float*)d_in[7];
    const float* ad2   = (const float*)d_in[8];
    const float* b2    = (const float*)d_in[9];
    float* out = (float*)d_out;

    const int Nn = N_NODES, E = N_EDGES, ET = N_TOT_EDGES;

    // workspace carve-up (256B aligned)
    char* ws = (char*)d_ws;
    size_t o = 0;
    auto carve = [&](size_t bytes) { char* p = ws + o; o = (o + bytes + 255) & ~(size_t)255; return p; };
    int*      off  = (int*)carve((Nn + 1) * sizeof(int));
    int*      cnt  = (int*)carve(Nn * sizeof(int));
    int*      cur  = (int*)carve(Nn * sizeof(int));
    int*      bsum = (int*)carve(256 * sizeof(int));
    int*      csr  = (int*)carve((size_t)ET * sizeof(int));
    unsigned* ew   = (unsigned*)carve((size_t)ET * sizeof(unsigned));
    float*    h1   = (float*)carve((size_t)Nn * HID * sizeof(float));  // chunk-major; reused as h2
    float*    als  = (float*)carve(Nn * sizeof(float));
    float*    ald  = (float*)carve(Nn * sizeof(float));
    float*    invd = (float*)carve(Nn * sizeof(float));
    float*    y1   = (float*)carve((size_t)Nn * HID * sizeof(float));
    float*    h2   = h1;

    const int nbN  = (Nn + 255) / 256;
    const int nbE  = (E + 255) / 256;
    const int nbET = (ET + 255) / 256;

    // CSR build
    k_init_cnt<<<nbN, 256, 0, stream>>>(cnt, cur, Nn);
    k_count<<<nbE, 256, 0, stream>>>(ei + E, cnt, E);
    k_scan1<<<nbN, 256, 0, stream>>>(cnt, off, bsum, Nn);
    k_scan2<<<1, 256, 0, stream>>>(bsum, nbN);
    k_scan3<<<nbN, 256, 0, stream>>>(off, bsum, Nn);
    k_fill<<<nbET, 256, 0, stream>>>(ei, off, cur, csr, E, Nn);

    const int nbEW = (Nn + 15) / 16;
    const int nbNode4 = (Nn + 3) / 4;

    // layer 1
    gemm_att<HID><<<(Nn + 31) / 32, 256, 0, stream>>>(x, W1, as1, ad1, h1, als, ald, Nn);
    k_edgew<<<nbEW, 256, 0, stream>>>(als, ald, off, csr, ew, invd, Nn);
    k_spmm<HID, true><<<nbNode4 * (HID / 16), 256, 0, stream>>>(
        h1, ew, invd, b1, off, y1, Nn);

    // layer 2
    gemm_att<OUT_CH><<<(Nn + 63) / 64, 256, 0, stream>>>(y1, W2, as2, ad2, h2, als, ald, Nn);
    k_edgew<<<nbEW, 256, 0, stream>>>(als, ald, off, csr, ew, invd, Nn);
    k_spmm<OUT_CH, false><<<nbNode4 * (OUT_CH / 16), 256, 0, stream>>>(
        h2, ew, invd, b2, off, out, Nn);
}

// Round 8
// 287.179 us; speedup vs baseline: 1.4074x; 1.2294x over previous
//
#include <hip/hip_runtime.h>
#include <hip/hip_bf16.h>

#define N_NODES 50000
#define IN_CH 128
#define HID 128
#define OUT_CH 64
#define N_EDGES 800000
#define N_TOT_EDGES (N_EDGES + N_NODES)         // + self loops
#define ET_PAD (N_TOT_EDGES + 3 * N_NODES)      // worst-case pad-to-4 per node

// ---------------- CSR build ----------------

__global__ void k_init_cnt(int* cnt, int* cur, int n) {
    int i = blockIdx.x * 256 + threadIdx.x;
    if (i < n) { cnt[i] = 1; cur[i] = 0; }   // self-loop contributes 1
}

__global__ void k_count(const int* __restrict__ dst_row, int* __restrict__ cnt, int e) {
    int i = blockIdx.x * 256 + threadIdx.x;
    if (i < e) atomicAdd(&cnt[dst_row[i]], 1);
}

// inclusive scan of PADDED counts -> off[i+1]; per-block sums to bsum.
// Segments padded to 4 so the SpMM can use aligned uint4 ew loads, no tail.
__global__ void k_scan1(const int* __restrict__ cnt, int* __restrict__ off,
                        int* __restrict__ bsum, int n) {
    __shared__ int s[256];
    int t = threadIdx.x;
    int i = blockIdx.x * 256 + t;
    int v = (i < n) ? ((cnt[i] + 3) & ~3) : 0;
    s[t] = v;
    __syncthreads();
    for (int d = 1; d < 256; d <<= 1) {
        int x = (t >= d) ? s[t - d] : 0;
        __syncthreads();
        s[t] += x;
        __syncthreads();
    }
    if (i < n) off[i + 1] = s[t];
    if (t == 255) bsum[blockIdx.x] = s[255];
}

__global__ void k_scan2(int* __restrict__ bsum, int nb) {  // single block, nb <= 256
    __shared__ int s[256];
    int t = threadIdx.x;
    int v = (t < nb) ? bsum[t] : 0;
    s[t] = v;
    __syncthreads();
    for (int d = 1; d < 256; d <<= 1) {
        int x = (t >= d) ? s[t - d] : 0;
        __syncthreads();
        s[t] += x;
        __syncthreads();
    }
    if (t < nb) bsum[t] = s[t] - v;  // exclusive prefix
}

__global__ void k_scan3(int* __restrict__ off, const int* __restrict__ bsum, int n) {
    int i = blockIdx.x * 256 + threadIdx.x;
    if (i < n) off[i + 1] += bsum[blockIdx.x];
    if (i == 0) off[0] = 0;
}

__global__ void k_fill(const int* __restrict__ ei, const int* __restrict__ off,
                       int* __restrict__ cur, int* __restrict__ csr, int e, int n) {
    int i = blockIdx.x * 256 + threadIdx.x;
    if (i >= e + n) return;
    int src, dst;
    if (i < e) { src = ei[i]; dst = ei[e + i]; }
    else       { src = dst = i - e; }
    int pos = off[dst] + atomicAdd(&cur[dst], 1);
    csr[pos] = src;
}

// ---------------- GEMM (h = X @ W) + fused attention dots ----------------
// W + X^T staged in LDS. H written CHUNK-MAJOR Hc[chunk][row][16] so the SpMM
// keeps one 3.2MB chunk resident in a single XCD's 4MB L2.
template<int N>
__global__ __launch_bounds__(256) void gemm_att(
        const float* __restrict__ X, const float* __restrict__ W,
        const float* __restrict__ asrc, const float* __restrict__ adst,
        float* __restrict__ Hc, float* __restrict__ als, float* __restrict__ ald,
        int M) {
    constexpr int K = 128;
    constexpr int TPR = N / 4;             // threads per row (32 or 16)
    constexpr int RPB = (256 / TPR) * 4;   // rows per block (32 or 64)
    __shared__ float Ws[K * N];
    __shared__ float Xt[K * RPB];          // transposed: Xt[k][row_local]
    const int t = threadIdx.x;
    const int r0 = blockIdx.x * RPB;

    for (int i = t * 4; i < K * N; i += 1024)
        *(float4*)&Ws[i] = *(const float4*)&W[i];
    for (int i = t * 4; i < RPB * K; i += 1024) {
        int rl = i / K, k0 = i % K;
        int row = r0 + rl;
        float4 v = make_float4(0.f, 0.f, 0.f, 0.f);
        if (row < M) v = *(const float4*)&X[(size_t)row * K + k0];
        Xt[(k0 + 0) * RPB + rl] = v.x;
        Xt[(k0 + 1) * RPB + rl] = v.y;
        Xt[(k0 + 2) * RPB + rl] = v.z;
        Xt[(k0 + 3) * RPB + rl] = v.w;
    }
    __syncthreads();

    const int col = (t % TPR) * 4;
    const int rg  = (t / TPR) * 4;
    float acc[4][4] = {};
    for (int k = 0; k < K; ++k) {
        float4 xv = *(const float4*)&Xt[k * RPB + rg];
        float4 wv = *(const float4*)&Ws[k * N + col];
        float xa[4] = {xv.x, xv.y, xv.z, xv.w};
        #pragma unroll
        for (int r = 0; r < 4; ++r) {
            acc[r][0] += xa[r] * wv.x;
            acc[r][1] += xa[r] * wv.y;
            acc[r][2] += xa[r] * wv.z;
            acc[r][3] += xa[r] * wv.w;
        }
    }

    float as0 = asrc[col], as1 = asrc[col+1], as2 = asrc[col+2], as3 = asrc[col+3];
    float ad0 = adst[col], ad1 = adst[col+1], ad2 = adst[col+2], ad3 = adst[col+3];
    const size_t cstride = (size_t)M * 16;
    #pragma unroll
    for (int r = 0; r < 4; ++r) {
        int row = r0 + rg + r;
        float ps = acc[r][0]*as0 + acc[r][1]*as1 + acc[r][2]*as2 + acc[r][3]*as3;
        float pd = acc[r][0]*ad0 + acc[r][1]*ad1 + acc[r][2]*ad2 + acc[r][3]*ad3;
        #pragma unroll
        for (int mask = 1; mask < TPR; mask <<= 1) {
            ps += __shfl_xor(ps, mask);
            pd += __shfl_xor(pd, mask);
        }
        if (row < M) {
            *(float4*)&Hc[(size_t)(col >> 4) * cstride + (size_t)row * 16 + (col & 15)] =
                make_float4(acc[r][0], acc[r][1], acc[r][2], acc[r][3]);
            if ((t % TPR) == 0) { als[row] = ps; ald[row] = pd; }
        }
    }
}

// ---------------- edge weights: packed u32 = (src<<16) | bf16(exp(leaky(e))) ----
// src < 65536 (N_NODES=50000) so 16 bits suffice. Denominator sums the ROUNDED
// bf16 weights so numerator/denominator are exactly consistent.
// Real degree comes from cnt[] (off[] is the padded layout); pad slots stay 0
// (src=0, w=+0.0) from the ew memset and contribute exactly nothing.
// No segment-max: scores are glorot-scale dot products (|e| < ~10), exp() is
// f32-safe and softmax ratios identical to the max-subtracted reference.
__global__ __launch_bounds__(256) void k_edgew(
        const float* __restrict__ als, const float* __restrict__ ald,
        const int* __restrict__ off, const int* __restrict__ cnt,
        const int* __restrict__ csr,
        unsigned* __restrict__ ew, float* __restrict__ invden, int n) {
    const int fl = threadIdx.x & 15;
    const int v = blockIdx.x * 16 + (threadIdx.x >> 4);
    if (v >= n) return;
    const int start = off[v], end = start + cnt[v];
    const float aldv = ald[v];
    float s = 0.f;
    for (int j = start + fl; j < end; j += 16) {
        int src = csr[j];
        float e = als[src] + aldv;
        e = e > 0.f ? e : 0.2f * e;
        float w = __expf(e);
        unsigned u = __float_as_uint(w);
        unsigned r = (u + 0x7fffu + ((u >> 16) & 1u)) >> 16;   // RNE to bf16
        ew[j] = ((unsigned)src << 16) | r;
        s += __uint_as_float(r << 16);
    }
    #pragma unroll
    for (int d = 1; d < 16; d <<= 1) s += __shfl_xor(s, d);
    if (fl == 0) invden[v] = 1.f / (s + 1e-16f);
}

// ---------------- chunked SpMM: out[v] = invden * sum_e w_e * Hc[src_e] ------------
// Wave = 4 nodes; each 16-lane sub owns ONE node, lane = one feature of the
// chunk. NO cross-lane ops anywhere: the sub's 16 lanes directly hold the
// node's 16 output features. Per 4 edges: one aligned uint4 ew broadcast load
// (segments padded to 4; pads are (src=0,w=0)) + 4 independent gathers + 4
// FMAs -> ~5 insts/edge, 4 gathers in flight. Per-sub trip counts may diverge
// freely (no shfl hazard).
// chunk = blockIdx.x % NCH -> round-robin block->XCD dispatch pins each chunk's
// 3.2MB Hc slice to one XCD's L2 (validated: FETCH == compulsory since r6).
template<int F, bool RELU>
__global__ __launch_bounds__(256) void k_spmm(
        const float* __restrict__ Hc, const unsigned* __restrict__ ew,
        const float* __restrict__ invden, const float* __restrict__ bias,
        const int* __restrict__ off, float* __restrict__ out, int n) {
    constexpr int NCH = F / 16;
    const int chunk = blockIdx.x % NCH;
    const int v = (blockIdx.x / NCH) * 16 + (threadIdx.x >> 4);
    if (v >= n) return;
    const int fl = threadIdx.x & 15;
    const int start = off[v], end = off[v + 1];   // padded: (end-start) % 4 == 0
    const float* __restrict__ Hch = Hc + (size_t)chunk * (size_t)n * 16 + fl;

    float a0 = 0.f, a1 = 0.f, a2 = 0.f, a3 = 0.f;
    for (int j = start; j < end; j += 4) {
        uint4 e4 = *(const uint4*)&ew[j];         // 16B broadcast within sub
        a0 += __uint_as_float(e4.x << 16) * Hch[(size_t)(e4.x >> 16) * 16];
        a1 += __uint_as_float(e4.y << 16) * Hch[(size_t)(e4.y >> 16) * 16];
        a2 += __uint_as_float(e4.z << 16) * Hch[(size_t)(e4.z >> 16) * 16];
        a3 += __uint_as_float(e4.w << 16) * Hch[(size_t)(e4.w >> 16) * 16];
    }
    float o = ((a0 + a1) + (a2 + a3)) * invden[v] + bias[chunk * 16 + fl];
    if (RELU) o = fmaxf(o, 0.f);
    out[(size_t)v * F + chunk * 16 + fl] = o;
}

// ---------------- launch ----------------

extern "C" void kernel_launch(void* const* d_in, const int* in_sizes, int n_in,
                              void* d_out, int out_size, void* d_ws, size_t ws_size,
                              hipStream_t stream) {
    const float* x     = (const float*)d_in[0];
    const int*   ei    = (const int*)d_in[1];
    const float* W1    = (const float*)d_in[2];
    const float* as1   = (const float*)d_in[3];
    const float* ad1   = (const float*)d_in[4];
    const float* b1    = (const float*)d_in[5];
    const float* W2    = (const float*)d_in[6];
    const float* as2   = (const float*)d_in[7];
    const float* ad2   = (const float*)d_in[8];
    const float* b2    = (const float*)d_in[9];
    float* out = (float*)d_out;

    const int Nn = N_NODES, E = N_EDGES, ET = N_TOT_EDGES;

    // workspace carve-up (256B aligned)
    char* ws = (char*)d_ws;
    size_t o = 0;
    auto carve = [&](size_t bytes) { char* p = ws + o; o = (o + bytes + 255) & ~(size_t)255; return p; };
    int*      off  = (int*)carve((Nn + 1) * sizeof(int));
    int*      cnt  = (int*)carve(Nn * sizeof(int));
    int*      cur  = (int*)carve(Nn * sizeof(int));
    int*      bsum = (int*)carve(256 * sizeof(int));
    int*      csr  = (int*)carve((size_t)ET_PAD * sizeof(int));
    unsigned* ew   = (unsigned*)carve((size_t)ET_PAD * sizeof(unsigned));
    float*    h1   = (float*)carve((size_t)Nn * HID * sizeof(float));  // chunk-major; reused as h2
    float*    als  = (float*)carve(Nn * sizeof(float));
    float*    ald  = (float*)carve(Nn * sizeof(float));
    float*    invd = (float*)carve(Nn * sizeof(float));
    float*    y1   = (float*)carve((size_t)Nn * HID * sizeof(float));
    float*    h2   = h1;

    const int nbN  = (Nn + 255) / 256;
    const int nbE  = (E + 255) / 256;
    const int nbET = (ET + 255) / 256;

    // CSR build (padded-to-4 segments)
    k_init_cnt<<<nbN, 256, 0, stream>>>(cnt, cur, Nn);
    k_count<<<nbE, 256, 0, stream>>>(ei + E, cnt, E);
    k_scan1<<<nbN, 256, 0, stream>>>(cnt, off, bsum, Nn);
    k_scan2<<<1, 256, 0, stream>>>(bsum, nbN);
    k_scan3<<<nbN, 256, 0, stream>>>(off, bsum, Nn);
    k_fill<<<nbET, 256, 0, stream>>>(ei, off, cur, csr, E, Nn);
    hipMemsetAsync(ew, 0, (size_t)ET_PAD * sizeof(unsigned), stream);  // pad slots -> (src=0, w=0)

    const int nbEW = (Nn + 15) / 16;
    const int nbN16 = (Nn + 15) / 16;

    // layer 1
    gemm_att<HID><<<(Nn + 31) / 32, 256, 0, stream>>>(x, W1, as1, ad1, h1, als, ald, Nn);
    k_edgew<<<nbEW, 256, 0, stream>>>(als, ald, off, cnt, csr, ew, invd, Nn);
    k_spmm<HID, true><<<nbN16 * (HID / 16), 256, 0, stream>>>(
        h1, ew, invd, b1, off, y1, Nn);

    // layer 2
    gemm_att<OUT_CH><<<(Nn + 63) / 64, 256, 0, stream>>>(y1, W2, as2, ad2, h2, als, ald, Nn);
    k_edgew<<<nbEW, 256, 0, stream>>>(als, ald, off, cnt, csr, ew, invd, Nn);
    k_spmm<OUT_CH, false><<<nbN16 * (OUT_CH / 16), 256, 0, stream>>>(
        h2, ew, invd, b2, off, out, Nn);
}

// Round 9
// 266.310 us; speedup vs baseline: 1.5177x; 1.0784x over previous
//
#include <hip/hip_runtime.h>
#include <hip/hip_bf16.h>

#define N_NODES 50000
#define IN_CH 128
#define HID 128
#define OUT_CH 64
#define N_EDGES 800000
#define N_TOT_EDGES (N_EDGES + N_NODES)         // + self loops
#define ET_PAD (N_TOT_EDGES + 3 * N_NODES)      // worst-case pad-to-4 per node

// ---------------- CSR build ----------------

__global__ void k_init_cnt(int* cnt, int* cur, int n) {
    int i = blockIdx.x * 256 + threadIdx.x;
    if (i < n) { cnt[i] = 1; cur[i] = 0; }   // self-loop contributes 1
}

__global__ void k_count(const int* __restrict__ dst_row, int* __restrict__ cnt, int e) {
    int i = blockIdx.x * 256 + threadIdx.x;
    if (i < e) atomicAdd(&cnt[dst_row[i]], 1);
}

// inclusive scan of PADDED counts -> off[i+1]; per-block sums to bsum.
// Segments padded to 4 so the SpMM can use aligned uint4 ew loads, no tail.
__global__ void k_scan1(const int* __restrict__ cnt, int* __restrict__ off,
                        int* __restrict__ bsum, int n) {
    __shared__ int s[256];
    int t = threadIdx.x;
    int i = blockIdx.x * 256 + t;
    int v = (i < n) ? ((cnt[i] + 3) & ~3) : 0;
    s[t] = v;
    __syncthreads();
    for (int d = 1; d < 256; d <<= 1) {
        int x = (t >= d) ? s[t - d] : 0;
        __syncthreads();
        s[t] += x;
        __syncthreads();
    }
    if (i < n) off[i + 1] = s[t];
    if (t == 255) bsum[blockIdx.x] = s[255];
}

__global__ void k_scan2(int* __restrict__ bsum, int nb) {  // single block, nb <= 256
    __shared__ int s[256];
    int t = threadIdx.x;
    int v = (t < nb) ? bsum[t] : 0;
    s[t] = v;
    __syncthreads();
    for (int d = 1; d < 256; d <<= 1) {
        int x = (t >= d) ? s[t - d] : 0;
        __syncthreads();
        s[t] += x;
        __syncthreads();
    }
    if (t < nb) bsum[t] = s[t] - v;  // exclusive prefix
}

__global__ void k_scan3(int* __restrict__ off, const int* __restrict__ bsum, int n) {
    int i = blockIdx.x * 256 + threadIdx.x;
    if (i < n) off[i + 1] += bsum[blockIdx.x];
    if (i == 0) off[0] = 0;
}

__global__ void k_fill(const int* __restrict__ ei, const int* __restrict__ off,
                       int* __restrict__ cur, int* __restrict__ csr, int e, int n) {
    int i = blockIdx.x * 256 + threadIdx.x;
    if (i >= e + n) return;
    int src, dst;
    if (i < e) { src = ei[i]; dst = ei[e + i]; }
    else       { src = dst = i - e; }
    int pos = off[dst] + atomicAdd(&cur[dst], 1);
    csr[pos] = src;
}

// ---------------- GEMM (h = X @ W) + fused attention dots ----------------
// W + X^T staged in LDS. H written CHUNK-MAJOR Hc[chunk][row][16] so the SpMM
// keeps one 3.2MB chunk resident in a single XCD's 4MB L2.
template<int N>
__global__ __launch_bounds__(256) void gemm_att(
        const float* __restrict__ X, const float* __restrict__ W,
        const float* __restrict__ asrc, const float* __restrict__ adst,
        float* __restrict__ Hc, float* __restrict__ als, float* __restrict__ ald,
        int M) {
    constexpr int K = 128;
    constexpr int TPR = N / 4;             // threads per row (32 or 16)
    constexpr int RPB = (256 / TPR) * 4;   // rows per block (32 or 64)
    __shared__ float Ws[K * N];
    __shared__ float Xt[K * RPB];          // transposed: Xt[k][row_local]
    const int t = threadIdx.x;
    const int r0 = blockIdx.x * RPB;

    for (int i = t * 4; i < K * N; i += 1024)
        *(float4*)&Ws[i] = *(const float4*)&W[i];
    for (int i = t * 4; i < RPB * K; i += 1024) {
        int rl = i / K, k0 = i % K;
        int row = r0 + rl;
        float4 v = make_float4(0.f, 0.f, 0.f, 0.f);
        if (row < M) v = *(const float4*)&X[(size_t)row * K + k0];
        Xt[(k0 + 0) * RPB + rl] = v.x;
        Xt[(k0 + 1) * RPB + rl] = v.y;
        Xt[(k0 + 2) * RPB + rl] = v.z;
        Xt[(k0 + 3) * RPB + rl] = v.w;
    }
    __syncthreads();

    const int col = (t % TPR) * 4;
    const int rg  = (t / TPR) * 4;
    float acc[4][4] = {};
    for (int k = 0; k < K; ++k) {
        float4 xv = *(const float4*)&Xt[k * RPB + rg];
        float4 wv = *(const float4*)&Ws[k * N + col];
        float xa[4] = {xv.x, xv.y, xv.z, xv.w};
        #pragma unroll
        for (int r = 0; r < 4; ++r) {
            acc[r][0] += xa[r] * wv.x;
            acc[r][1] += xa[r] * wv.y;
            acc[r][2] += xa[r] * wv.z;
            acc[r][3] += xa[r] * wv.w;
        }
    }

    float as0 = asrc[col], as1 = asrc[col+1], as2 = asrc[col+2], as3 = asrc[col+3];
    float ad0 = adst[col], ad1 = adst[col+1], ad2 = adst[col+2], ad3 = adst[col+3];
    const size_t cstride = (size_t)M * 16;
    #pragma unroll
    for (int r = 0; r < 4; ++r) {
        int row = r0 + rg + r;
        float ps = acc[r][0]*as0 + acc[r][1]*as1 + acc[r][2]*as2 + acc[r][3]*as3;
        float pd = acc[r][0]*ad0 + acc[r][1]*ad1 + acc[r][2]*ad2 + acc[r][3]*ad3;
        #pragma unroll
        for (int mask = 1; mask < TPR; mask <<= 1) {
            ps += __shfl_xor(ps, mask);
            pd += __shfl_xor(pd, mask);
        }
        if (row < M) {
            *(float4*)&Hc[(size_t)(col >> 4) * cstride + (size_t)row * 16 + (col & 15)] =
                make_float4(acc[r][0], acc[r][1], acc[r][2], acc[r][3]);
            if ((t % TPR) == 0) { als[row] = ps; ald[row] = pd; }
        }
    }
}

// ---------------- edge weights: packed u32 = (src<<16) | bf16(exp(leaky(e))) ----
// src < 65536 (N_NODES=50000) so 16 bits suffice. Denominator sums the ROUNDED
// bf16 weights so numerator/denominator are exactly consistent.
// Real degree comes from cnt[] (off[] is the padded layout); pad slots stay 0
// (src=0, w=+0.0) from the ew memset and contribute exactly nothing.
// No segment-max: scores are glorot-scale dot products (|e| < ~10), exp() is
// f32-safe and softmax ratios identical to the max-subtracted reference.
__global__ __launch_bounds__(256) void k_edgew(
        const float* __restrict__ als, const float* __restrict__ ald,
        const int* __restrict__ off, const int* __restrict__ cnt,
        const int* __restrict__ csr,
        unsigned* __restrict__ ew, float* __restrict__ invden, int n) {
    const int fl = threadIdx.x & 15;
    const int v = blockIdx.x * 16 + (threadIdx.x >> 4);
    if (v >= n) return;
    const int start = off[v], end = start + cnt[v];
    const float aldv = ald[v];
    float s = 0.f;
    for (int j = start + fl; j < end; j += 16) {
        int src = csr[j];
        float e = als[src] + aldv;
        e = e > 0.f ? e : 0.2f * e;
        float w = __expf(e);
        unsigned u = __float_as_uint(w);
        unsigned r = (u + 0x7fffu + ((u >> 16) & 1u)) >> 16;   // RNE to bf16
        ew[j] = ((unsigned)src << 16) | r;
        s += __uint_as_float(r << 16);
    }
    #pragma unroll
    for (int d = 1; d < 16; d <<= 1) s += __shfl_xor(s, d);
    if (fl == 0) invden[v] = 1.f / (s + 1e-16f);
}

// ---------------- chunked SpMM: out[v] = invden * sum_e w_e * Hc[src_e] ------------
// Wave = 16 nodes; each 4-lane sub owns ONE node, lane = one FEATURE QUAD
// (float4) of the 16-feature chunk. One gather instruction fetches 16
// independent 64B lines (1KB useful) -> 4x the memory-level parallelism per
// issued instruction vs the 16-lane-sub layout, 4x fewer waves.
// Per 8 edges: 2 uint4 ew broadcast loads + 8 independent float4 gathers +
// 32 fmac. No cross-lane ops anywhere -> per-sub loop bounds diverge safely.
// Segments padded to 4 (pads are (src=0,w=0)); tail is exactly 0 or 1 quad.
// chunk = blockIdx.x % NCH -> round-robin block->XCD dispatch pins each chunk's
// 3.2MB Hc slice to one XCD's L2 (validated: FETCH == compulsory since r6).
template<int F, bool RELU>
__global__ __launch_bounds__(256) void k_spmm(
        const float* __restrict__ Hc, const unsigned* __restrict__ ew,
        const float* __restrict__ invden, const float* __restrict__ bias,
        const int* __restrict__ off, float* __restrict__ out, int n) {
    constexpr int NCH = F / 16;
    const int chunk = blockIdx.x % NCH;
    const int v = (blockIdx.x / NCH) * 64 + (threadIdx.x >> 2);
    if (v >= n) return;
    const int q = threadIdx.x & 3;                // feature quad 0..3
    const int start = off[v], end = off[v + 1];   // padded: (end-start) % 4 == 0
    const float* __restrict__ Hch = Hc + (size_t)chunk * (size_t)n * 16 + q * 4;

    float4 a0 = make_float4(0.f, 0.f, 0.f, 0.f);
    float4 a1 = make_float4(0.f, 0.f, 0.f, 0.f);
    float4 a2 = make_float4(0.f, 0.f, 0.f, 0.f);
    float4 a3 = make_float4(0.f, 0.f, 0.f, 0.f);

    #define GAT(E, A)                                                  \
        {                                                              \
            float w_ = __uint_as_float((E) << 16);                     \
            float4 h_ = *(const float4*)&Hch[(size_t)((E) >> 16) * 16];\
            A.x += w_ * h_.x; A.y += w_ * h_.y;                        \
            A.z += w_ * h_.z; A.w += w_ * h_.w;                        \
        }

    int j = start;
    for (; j + 4 < end; j += 8) {                 // two quads per iteration
        uint4 eA = *(const uint4*)&ew[j];
        uint4 eB = *(const uint4*)&ew[j + 4];
        GAT(eA.x, a0) GAT(eA.y, a1) GAT(eA.z, a2) GAT(eA.w, a3)
        GAT(eB.x, a0) GAT(eB.y, a1) GAT(eB.z, a2) GAT(eB.w, a3)
    }
    if (j < end) {                                // remaining single quad
        uint4 eA = *(const uint4*)&ew[j];
        GAT(eA.x, a0) GAT(eA.y, a1) GAT(eA.z, a2) GAT(eA.w, a3)
    }
    #undef GAT

    const float inv = invden[v];
    const float4 b = *(const float4*)&bias[chunk * 16 + q * 4];
    float4 o;
    o.x = (a0.x + a1.x + a2.x + a3.x) * inv + b.x;
    o.y = (a0.y + a1.y + a2.y + a3.y) * inv + b.y;
    o.z = (a0.z + a1.z + a2.z + a3.z) * inv + b.z;
    o.w = (a0.w + a1.w + a2.w + a3.w) * inv + b.w;
    if (RELU) {
        o.x = fmaxf(o.x, 0.f); o.y = fmaxf(o.y, 0.f);
        o.z = fmaxf(o.z, 0.f); o.w = fmaxf(o.w, 0.f);
    }
    *(float4*)&out[(size_t)v * F + chunk * 16 + q * 4] = o;
}

// ---------------- launch ----------------

extern "C" void kernel_launch(void* const* d_in, const int* in_sizes, int n_in,
                              void* d_out, int out_size, void* d_ws, size_t ws_size,
                              hipStream_t stream) {
    const float* x     = (const float*)d_in[0];
    const int*   ei    = (const int*)d_in[1];
    const float* W1    = (const float*)d_in[2];
    const float* as1   = (const float*)d_in[3];
    const float* ad1   = (const float*)d_in[4];
    const float* b1    = (const float*)d_in[5];
    const float* W2    = (const float*)d_in[6];
    const float* as2   = (const float*)d_in[7];
    const float* ad2   = (const float*)d_in[8];
    const float* b2    = (const float*)d_in[9];
    float* out = (float*)d_out;

    const int Nn = N_NODES, E = N_EDGES, ET = N_TOT_EDGES;

    // workspace carve-up (256B aligned)
    char* ws = (char*)d_ws;
    size_t o = 0;
    auto carve = [&](size_t bytes) { char* p = ws + o; o = (o + bytes + 255) & ~(size_t)255; return p; };
    int*      off  = (int*)carve((Nn + 1) * sizeof(int));
    int*      cnt  = (int*)carve(Nn * sizeof(int));
    int*      cur  = (int*)carve(Nn * sizeof(int));
    int*      bsum = (int*)carve(256 * sizeof(int));
    int*      csr  = (int*)carve((size_t)ET_PAD * sizeof(int));
    unsigned* ew   = (unsigned*)carve((size_t)ET_PAD * sizeof(unsigned));
    float*    h1   = (float*)carve((size_t)Nn * HID * sizeof(float));  // chunk-major; reused as h2
    float*    als  = (float*)carve(Nn * sizeof(float));
    float*    ald  = (float*)carve(Nn * sizeof(float));
    float*    invd = (float*)carve(Nn * sizeof(float));
    float*    y1   = (float*)carve((size_t)Nn * HID * sizeof(float));
    float*    h2   = h1;

    const int nbN  = (Nn + 255) / 256;
    const int nbE  = (E + 255) / 256;
    const int nbET = (ET + 255) / 256;

    // CSR build (padded-to-4 segments)
    k_init_cnt<<<nbN, 256, 0, stream>>>(cnt, cur, Nn);
    k_count<<<nbE, 256, 0, stream>>>(ei + E, cnt, E);
    k_scan1<<<nbN, 256, 0, stream>>>(cnt, off, bsum, Nn);
    k_scan2<<<1, 256, 0, stream>>>(bsum, nbN);
    k_scan3<<<nbN, 256, 0, stream>>>(off, bsum, Nn);
    k_fill<<<nbET, 256, 0, stream>>>(ei, off, cur, csr, E, Nn);
    hipMemsetAsync(ew, 0, (size_t)ET_PAD * sizeof(unsigned), stream);  // pad slots -> (src=0, w=0)

    const int nbEW  = (Nn + 15) / 16;
    const int nbN64 = (Nn + 63) / 64;

    // layer 1
    gemm_att<HID><<<(Nn + 31) / 32, 256, 0, stream>>>(x, W1, as1, ad1, h1, als, ald, Nn);
    k_edgew<<<nbEW, 256, 0, stream>>>(als, ald, off, cnt, csr, ew, invd, Nn);
    k_spmm<HID, true><<<nbN64 * (HID / 16), 256, 0, stream>>>(
        h1, ew, invd, b1, off, y1, Nn);

    // layer 2
    gemm_att<OUT_CH><<<(Nn + 63) / 64, 256, 0, stream>>>(y1, W2, as2, ad2, h2, als, ald, Nn);
    k_edgew<<<nbEW, 256, 0, stream>>>(als, ald, off, cnt, csr, ew, invd, Nn);
    k_spmm<OUT_CH, false><<<nbN64 * (OUT_CH / 16), 256, 0, stream>>>(
        h2, ew, invd, b2, off, out, Nn);
}

// Round 10
// 245.520 us; speedup vs baseline: 1.6463x; 1.0847x over previous
//
#include <hip/hip_runtime.h>
#include <hip/hip_bf16.h>

#define N_NODES 50000
#define IN_CH 128
#define HID 128
#define OUT_CH 64
#define N_EDGES 800000
#define N_TOT_EDGES (N_EDGES + N_NODES)         // + self loops
#define ET_PAD (N_TOT_EDGES + 3 * N_NODES)      // worst-case pad-to-4 per node

// ---------------- CSR build ----------------

__global__ void k_init(int* cnt, int* cur, float* alsA, float* aldA,
                       float* alsB, float* aldB, int n) {
    int i = blockIdx.x * 256 + threadIdx.x;
    if (i < n) {
        cnt[i] = 1; cur[i] = 0;              // self-loop contributes 1
        alsA[i] = 0.f; aldA[i] = 0.f;        // per-layer attention-dot accumulators
        alsB[i] = 0.f; aldB[i] = 0.f;        // (gemm atomically accumulates tile partials)
    }
}

__global__ void k_count(const int* __restrict__ dst_row, int* __restrict__ cnt, int e) {
    int i = blockIdx.x * 256 + threadIdx.x;
    if (i < e) atomicAdd(&cnt[dst_row[i]], 1);
}

// inclusive scan of PADDED counts -> off[i+1]; per-block sums to bsum.
// Segments padded to 4 so the SpMM can use aligned uint4 ew loads, no tail.
__global__ void k_scan1(const int* __restrict__ cnt, int* __restrict__ off,
                        int* __restrict__ bsum, int n) {
    __shared__ int s[256];
    int t = threadIdx.x;
    int i = blockIdx.x * 256 + t;
    int v = (i < n) ? ((cnt[i] + 3) & ~3) : 0;
    s[t] = v;
    __syncthreads();
    for (int d = 1; d < 256; d <<= 1) {
        int x = (t >= d) ? s[t - d] : 0;
        __syncthreads();
        s[t] += x;
        __syncthreads();
    }
    if (i < n) off[i + 1] = s[t];
    if (t == 255) bsum[blockIdx.x] = s[255];
}

__global__ void k_scan2(int* __restrict__ bsum, int nb) {  // single block, nb <= 256
    __shared__ int s[256];
    int t = threadIdx.x;
    int v = (t < nb) ? bsum[t] : 0;
    s[t] = v;
    __syncthreads();
    for (int d = 1; d < 256; d <<= 1) {
        int x = (t >= d) ? s[t - d] : 0;
        __syncthreads();
        s[t] += x;
        __syncthreads();
    }
    if (t < nb) bsum[t] = s[t] - v;  // exclusive prefix
}

__global__ void k_scan3(int* __restrict__ off, const int* __restrict__ bsum, int n) {
    int i = blockIdx.x * 256 + threadIdx.x;
    if (i < n) off[i + 1] += bsum[blockIdx.x];
    if (i == 0) off[0] = 0;
}

__global__ void k_fill(const int* __restrict__ ei, const int* __restrict__ off,
                       int* __restrict__ cur, int* __restrict__ csr, int e, int n) {
    int i = blockIdx.x * 256 + threadIdx.x;
    if (i >= e + n) return;
    int src, dst;
    if (i < e) { src = ei[i]; dst = ei[e + i]; }
    else       { src = dst = i - e; }
    int pos = off[dst] + atomicAdd(&cur[dst], 1);
    csr[pos] = src;
}

// ---------------- GEMM (h = X @ W) + fused attention dots ----------------
// Only W (the reused operand: 782 row-blocks share it) is staged in LDS —
// a 64-col tile = 32KB -> 4-5 blocks/CU (was 80KB -> 2 blocks, 16% occupancy,
// 6.2M bank conflicts from the transposed-X staging; both eliminated).
// X streams from global: 16 lanes/row-group read the same float4 -> broadcast.
// 64 rows x 64 cols per block; thread = 4 rows x 4 cols.
// H written CHUNK-MAJOR Hc[chunk][row][16] (chunk = 16 feats = 3.2MB slice,
// XCD-L2-resident for the SpMM). Attention dots: per-tile partial reduced over
// the 16 col-lanes (shfl_xor), one atomicAdd per (row, col-tile) into the
// zero-initialized per-layer buffers (2 commutative adds -> deterministic).
template<int N>
__global__ __launch_bounds__(256) void gemm_att(
        const float* __restrict__ X, const float* __restrict__ W,
        const float* __restrict__ asrc, const float* __restrict__ adst,
        float* __restrict__ Hc, float* __restrict__ als, float* __restrict__ ald,
        int M) {
    constexpr int K = 128;
    constexpr int CT = N / 64;                 // col tiles (2 or 1)
    __shared__ float Ws[K * 64];               // 32 KB
    const int ct = blockIdx.x % CT;
    const int r0 = (blockIdx.x / CT) * 64;
    const int t  = threadIdx.x;
    const int c  = t & 15;                     // col group (4 cols each)
    const int rg = t >> 4;                     // row group (4 rows each)
    const int col = ct * 64 + c * 4;

    // stage W col-tile: linear float4 copies, conflict-free
    for (int i = t * 4; i < K * 64; i += 1024) {
        int k = i >> 6, cc = i & 63;
        *(float4*)&Ws[i] = *(const float4*)&W[(size_t)k * N + ct * 64 + cc];
    }
    __syncthreads();

    // clamp OOB rows to M-1 (results discarded at write)
    const float* Xr[4];
    #pragma unroll
    for (int r = 0; r < 4; ++r) {
        int row = r0 + rg * 4 + r; if (row >= M) row = M - 1;
        Xr[r] = X + (size_t)row * K;
    }

    float acc[4][4] = {};
    for (int k0 = 0; k0 < K; k0 += 4) {
        float4 xv[4], wv[4];
        #pragma unroll
        for (int r = 0; r < 4; ++r) xv[r] = *(const float4*)&Xr[r][k0];
        #pragma unroll
        for (int u = 0; u < 4; ++u) wv[u] = *(const float4*)&Ws[(k0 + u) * 64 + c * 4];
        #pragma unroll
        for (int r = 0; r < 4; ++r) {
            float xa[4] = {xv[r].x, xv[r].y, xv[r].z, xv[r].w};
            #pragma unroll
            for (int u = 0; u < 4; ++u) {
                acc[r][0] += xa[u] * wv[u].x;
                acc[r][1] += xa[u] * wv[u].y;
                acc[r][2] += xa[u] * wv[u].z;
                acc[r][3] += xa[u] * wv[u].w;
            }
        }
    }

    const float as0 = asrc[col], as1 = asrc[col+1], as2 = asrc[col+2], as3 = asrc[col+3];
    const float ad0 = adst[col], ad1 = adst[col+1], ad2 = adst[col+2], ad3 = adst[col+3];
    const size_t cstride = (size_t)M * 16;
    float* __restrict__ Hq = Hc + (size_t)(col >> 4) * cstride + (col & 15);
    #pragma unroll
    for (int r = 0; r < 4; ++r) {
        int row = r0 + rg * 4 + r;
        float ps = acc[r][0]*as0 + acc[r][1]*as1 + acc[r][2]*as2 + acc[r][3]*as3;
        float pd = acc[r][0]*ad0 + acc[r][1]*ad1 + acc[r][2]*ad2 + acc[r][3]*ad3;
        #pragma unroll
        for (int mask = 1; mask < 16; mask <<= 1) {   // reduce over 16 col-groups
            ps += __shfl_xor(ps, mask);
            pd += __shfl_xor(pd, mask);
        }
        if (row < M) {
            *(float4*)&Hq[(size_t)row * 16] =
                make_float4(acc[r][0], acc[r][1], acc[r][2], acc[r][3]);
            if (c == 0) {
                atomicAdd(&als[row], ps);
                atomicAdd(&ald[row], pd);
            }
        }
    }
}

// ---------------- edge weights: packed u32 = (src<<16) | bf16(exp(leaky(e))) ----
// src < 65536 (N_NODES=50000) so 16 bits suffice. Denominator sums the ROUNDED
// bf16 weights so numerator/denominator are exactly consistent.
// Real degree comes from cnt[] (off[] is the padded layout); pad slots stay 0
// (src=0, w=+0.0) from the ew memset and contribute exactly nothing.
// No segment-max: scores are glorot-scale dot products (|e| < ~10), exp() is
// f32-safe and softmax ratios identical to the max-subtracted reference.
__global__ __launch_bounds__(256) void k_edgew(
        const float* __restrict__ als, const float* __restrict__ ald,
        const int* __restrict__ off, const int* __restrict__ cnt,
        const int* __restrict__ csr,
        unsigned* __restrict__ ew, float* __restrict__ invden, int n) {
    const int fl = threadIdx.x & 15;
    const int v = blockIdx.x * 16 + (threadIdx.x >> 4);
    if (v >= n) return;
    const int start = off[v], end = start + cnt[v];
    const float aldv = ald[v];
    float s = 0.f;
    for (int j = start + fl; j < end; j += 16) {
        int src = csr[j];
        float e = als[src] + aldv;
        e = e > 0.f ? e : 0.2f * e;
        float w = __expf(e);
        unsigned u = __float_as_uint(w);
        unsigned r = (u + 0x7fffu + ((u >> 16) & 1u)) >> 16;   // RNE to bf16
        ew[j] = ((unsigned)src << 16) | r;
        s += __uint_as_float(r << 16);
    }
    #pragma unroll
    for (int d = 1; d < 16; d <<= 1) s += __shfl_xor(s, d);
    if (fl == 0) invden[v] = 1.f / (s + 1e-16f);
}

// ---------------- chunked SpMM: out[v] = invden * sum_e w_e * Hc[src_e] ------------
// Wave = 16 nodes; each 4-lane sub owns ONE node, lane = one FEATURE QUAD
// (float4) of the 16-feature chunk. One gather instruction fetches 16
// independent 64B lines (1KB useful). No cross-lane ops anywhere -> per-sub
// loop bounds diverge safely. Segments padded to 4 (pads are (src=0,w=0)).
// chunk = blockIdx.x % NCH -> round-robin block->XCD dispatch pins each chunk's
// 3.2MB Hc slice to one XCD's L2 (validated: FETCH == compulsory since r6).
template<int F, bool RELU>
__global__ __launch_bounds__(256) void k_spmm(
        const float* __restrict__ Hc, const unsigned* __restrict__ ew,
        const float* __restrict__ invden, const float* __restrict__ bias,
        const int* __restrict__ off, float* __restrict__ out, int n) {
    constexpr int NCH = F / 16;
    const int chunk = blockIdx.x % NCH;
    const int v = (blockIdx.x / NCH) * 64 + (threadIdx.x >> 2);
    if (v >= n) return;
    const int q = threadIdx.x & 3;                // feature quad 0..3
    const int start = off[v], end = off[v + 1];   // padded: (end-start) % 4 == 0
    const float* __restrict__ Hch = Hc + (size_t)chunk * (size_t)n * 16 + q * 4;

    float4 a0 = make_float4(0.f, 0.f, 0.f, 0.f);
    float4 a1 = make_float4(0.f, 0.f, 0.f, 0.f);
    float4 a2 = make_float4(0.f, 0.f, 0.f, 0.f);
    float4 a3 = make_float4(0.f, 0.f, 0.f, 0.f);

    #define GAT(E, A)                                                  \
        {                                                              \
            float w_ = __uint_as_float((E) << 16);                     \
            float4 h_ = *(const float4*)&Hch[(size_t)((E) >> 16) * 16];\
            A.x += w_ * h_.x; A.y += w_ * h_.y;                        \
            A.z += w_ * h_.z; A.w += w_ * h_.w;                        \
        }

    int j = start;
    for (; j + 4 < end; j += 8) {                 // two quads per iteration
        uint4 eA = *(const uint4*)&ew[j];
        uint4 eB = *(const uint4*)&ew[j + 4];
        GAT(eA.x, a0) GAT(eA.y, a1) GAT(eA.z, a2) GAT(eA.w, a3)
        GAT(eB.x, a0) GAT(eB.y, a1) GAT(eB.z, a2) GAT(eB.w, a3)
    }
    if (j < end) {                                // remaining single quad
        uint4 eA = *(const uint4*)&ew[j];
        GAT(eA.x, a0) GAT(eA.y, a1) GAT(eA.z, a2) GAT(eA.w, a3)
    }
    #undef GAT

    const float inv = invden[v];
    const float4 b = *(const float4*)&bias[chunk * 16 + q * 4];
    float4 o;
    o.x = (a0.x + a1.x + a2.x + a3.x) * inv + b.x;
    o.y = (a0.y + a1.y + a2.y + a3.y) * inv + b.y;
    o.z = (a0.z + a1.z + a2.z + a3.z) * inv + b.z;
    o.w = (a0.w + a1.w + a2.w + a3.w) * inv + b.w;
    if (RELU) {
        o.x = fmaxf(o.x, 0.f); o.y = fmaxf(o.y, 0.f);
        o.z = fmaxf(o.z, 0.f); o.w = fmaxf(o.w, 0.f);
    }
    *(float4*)&out[(size_t)v * F + chunk * 16 + q * 4] = o;
}

// ---------------- launch ----------------

extern "C" void kernel_launch(void* const* d_in, const int* in_sizes, int n_in,
                              void* d_out, int out_size, void* d_ws, size_t ws_size,
                              hipStream_t stream) {
    const float* x     = (const float*)d_in[0];
    const int*   ei    = (const int*)d_in[1];
    const float* W1    = (const float*)d_in[2];
    const float* as1   = (const float*)d_in[3];
    const float* ad1   = (const float*)d_in[4];
    const float* b1    = (const float*)d_in[5];
    const float* W2    = (const float*)d_in[6];
    const float* as2   = (const float*)d_in[7];
    const float* ad2   = (const float*)d_in[8];
    const float* b2    = (const float*)d_in[9];
    float* out = (float*)d_out;

    const int Nn = N_NODES, E = N_EDGES, ET = N_TOT_EDGES;

    // workspace carve-up (256B aligned)
    char* ws = (char*)d_ws;
    size_t o = 0;
    auto carve = [&](size_t bytes) { char* p = ws + o; o = (o + bytes + 255) & ~(size_t)255; return p; };
    int*      off  = (int*)carve((Nn + 1) * sizeof(int));
    int*      cnt  = (int*)carve(Nn * sizeof(int));
    int*      cur  = (int*)carve(Nn * sizeof(int));
    int*      bsum = (int*)carve(256 * sizeof(int));
    int*      csr  = (int*)carve((size_t)ET_PAD * sizeof(int));
    unsigned* ew   = (unsigned*)carve((size_t)ET_PAD * sizeof(unsigned));
    float*    h1   = (float*)carve((size_t)Nn * HID * sizeof(float));  // chunk-major; reused as h2
    float*    alsA = (float*)carve(Nn * sizeof(float));
    float*    aldA = (float*)carve(Nn * sizeof(float));
    float*    alsB = (float*)carve(Nn * sizeof(float));
    float*    aldB = (float*)carve(Nn * sizeof(float));
    float*    invd = (float*)carve(Nn * sizeof(float));
    float*    y1   = (float*)carve((size_t)Nn * HID * sizeof(float));
    float*    h2   = h1;

    const int nbN  = (Nn + 255) / 256;
    const int nbE  = (E + 255) / 256;
    const int nbET = (ET + 255) / 256;

    // CSR build (padded-to-4 segments)
    k_init<<<nbN, 256, 0, stream>>>(cnt, cur, alsA, aldA, alsB, aldB, Nn);
    k_count<<<nbE, 256, 0, stream>>>(ei + E, cnt, E);
    k_scan1<<<nbN, 256, 0, stream>>>(cnt, off, bsum, Nn);
    k_scan2<<<1, 256, 0, stream>>>(bsum, nbN);
    k_scan3<<<nbN, 256, 0, stream>>>(off, bsum, Nn);
    k_fill<<<nbET, 256, 0, stream>>>(ei, off, cur, csr, E, Nn);
    hipMemsetAsync(ew, 0, (size_t)ET_PAD * sizeof(unsigned), stream);  // pad slots -> (src=0, w=0)

    const int nbEW  = (Nn + 15) / 16;
    const int nbN64 = (Nn + 63) / 64;

    // layer 1
    gemm_att<HID><<<nbN64 * (HID / 64), 256, 0, stream>>>(x, W1, as1, ad1, h1, alsA, aldA, Nn);
    k_edgew<<<nbEW, 256, 0, stream>>>(alsA, aldA, off, cnt, csr, ew, invd, Nn);
    k_spmm<HID, true><<<nbN64 * (HID / 16), 256, 0, stream>>>(
        h1, ew, invd, b1, off, y1, Nn);

    // layer 2
    gemm_att<OUT_CH><<<nbN64 * (OUT_CH / 64), 256, 0, stream>>>(y1, W2, as2, ad2, h2, alsB, aldB, Nn);
    k_edgew<<<nbEW, 256, 0, stream>>>(alsB, aldB, off, cnt, csr, ew, invd, Nn);
    k_spmm<OUT_CH, false><<<nbN64 * (OUT_CH / 16), 256, 0, stream>>>(
        h2, ew, invd, b2, off, out, Nn);
}